// Round 8
// baseline (259.704 us; speedup 1.0000x reference)
//
#include <hip/hip_runtime.h>

// ---------------- problem constants ----------------
#define BATCH     16
#define T_LEN     480000
#define PAD       512
#define TPAD      481024      // T_LEN + 2*PAD
#define HOP       256
#define NFRAMES   1876        // (TPAD - NFFT)/HOP + 1
#define NOUTROW   1026        // 513 freqs * 2 (re,im interleaved)
#define KTOT      1024
#define BCOLS     1152        // bmat rows built (cols 1026..1151 zero)
#define XPSTRIDE  493568      // proven xp row stride (18.15 MB total workspace)

// ---------------- GEMM tile config (m201-style 8-phase, K-granular 32) ----
#define BM        256         // frames per block
#define BN        256         // cols per block (N padded to 1280 via read-clamp)
#define BK        32          // K per tile
#define NTILES    32          // KTOT/BK
#define TILEA     16384       // 256 rows x 32 k x 2B
#define BUFBYTES  32768       // A half + B half per K-tile
#define NBUF      3           // rotation depth; 96 KB LDS total
#define LDSBYTES  (NBUF * BUFBYTES)

typedef __attribute__((ext_vector_type(8))) short short8;
typedef __attribute__((ext_vector_type(4))) float floatx4;

#define GPTR(p) (const __attribute__((address_space(1))) void*)(p)
#define LPTR(p) (__attribute__((address_space(3))) void*)(p)

__device__ __forceinline__ unsigned short f2bf(float f) {
  union { float f; unsigned int u; } v; v.f = f;
  unsigned int u = v.u;
  return (unsigned short)((u + 0x7FFFu + ((u >> 16) & 1u)) >> 16); // RNE
}

// Reflect-padded signal as bf16, row stride XPSTRIDE, tail zero-filled.
__global__ __launch_bounds__(256) void build_xp(const float* __restrict__ x,
                                                unsigned short* __restrict__ xp) {
  const int i0 = (blockIdx.x * 256 + threadIdx.x) * 8;
  const int b  = blockIdx.y;
  const float* xb = x + (size_t)b * T_LEN;
  const int j0 = i0 - PAD;
  union { short8 v; unsigned short u[8]; } o;
  if (j0 >= 0 && j0 + 8 <= T_LEN) {
    const float4 lo = *(const float4*)(xb + j0);
    const float4 hi = *(const float4*)(xb + j0 + 4);
    o.u[0] = f2bf(lo.x); o.u[1] = f2bf(lo.y); o.u[2] = f2bf(lo.z); o.u[3] = f2bf(lo.w);
    o.u[4] = f2bf(hi.x); o.u[5] = f2bf(hi.y); o.u[6] = f2bf(hi.z); o.u[7] = f2bf(hi.w);
  } else {
#pragma unroll
    for (int e = 0; e < 8; ++e) {
      const int i = i0 + e;
      unsigned short v = 0;
      if (i < TPAD) {
        int j = i - PAD;
        if (j < 0) j = -j;
        if (j >= T_LEN) j = 2 * T_LEN - 2 - j;
        v = f2bf(xb[j]);
      }
      o.u[e] = v;
    }
  }
  *(short8*)(xp + (size_t)b * XPSTRIDE + i0) = o.v;
}

// Basis matrix bmat[jcol][k], jcol in [0,1152): 2f -> cos*w, 2f+1 -> -sin*w.
__global__ __launch_bounds__(256) void build_bmat(const float* __restrict__ win,
                                                  unsigned short* __restrict__ bm) {
  const int id = blockIdx.x * 256 + threadIdx.x;
  const int j  = id >> 7;
  const int k0 = (id & 127) * 8;
  union { short8 v; unsigned short u[8]; } o;
  if (j < NOUTROW) {
    const int f = j >> 1;
    const float4 w0 = *(const float4*)(win + k0);
    const float4 w1 = *(const float4*)(win + k0 + 4);
    const float wv[8] = {w0.x, w0.y, w0.z, w0.w, w1.x, w1.y, w1.z, w1.w};
#pragma unroll
    for (int e = 0; e < 8; ++e) {
      const int r = (f * (k0 + e)) & (KTOT - 1);
      const float ang = (float)r * 6.1359231515e-3f;  // 2*pi/1024
      const float c = __cosf(ang), s = __sinf(ang);
      o.u[e] = f2bf(((j & 1) ? -s : c) * wv[e]);
    }
  } else {
#pragma unroll
    for (int e = 0; e < 8; ++e) o.u[e] = 0;
  }
  *(short8*)(bm + (size_t)j * KTOT + k0) = o.v;
}

// 256x256x1024 GEMM tile, 8 waves (2M x 4N), wave tile 128x64 (intensity
// 42.7 FLOP/B -> MFMA-bound). K streamed in 32-wide tiles through a 3-buffer
// LDS rotation staged by global_load_lds; 2 phases per tile, each
// {ds_read subtile | issue 2 gload_lds | s_barrier | 16 MFMA | s_barrier};
// counted vmcnt(4) once per tile (loads span 4 phases, never drained).
// LDS layout [kq][row/col] -> lane-consecutive 16B frag reads, conflict-free.
__global__ __launch_bounds__(512, 2) void stft_gemm(const unsigned short* __restrict__ xp,
                                                    const unsigned short* __restrict__ bmat,
                                                    float* __restrict__ out) {
  extern __shared__ char smemc[];          // LDSBYTES = 96 KB

  const int tid  = threadIdx.x;            // 0..511
  const int lane = tid & 63;
  const int wv   = tid >> 6;               // 0..7
  const int wm   = wv >> 2;                // 0..1 : M 128-slice
  const int wn   = wv & 3;                 // 0..3 : N 64-slice
  const int L    = lane & 15;
  const int quad = lane >> 4;
  const int b    = blockIdx.x >> 3;
  const int t0   = (blockIdx.x & 7) * BM;  // frame base, <=1792
  const int j0   = blockIdx.y * BN;        // 0..1024 step 256

  // ---- staging sources: thread t owns chunks {t, t+512} of each tile ----
  // A chunk ca = kq*256 + row holds A[row][kq*8..+7] of the tile.
  // Tail M-tile rows >=1876 read past the xp row into defined workspace
  // (next batch row / bmat) -- garbage feeds only never-stored frames.
  const int srow = tid & 255;
  const int skq  = tid >> 8;               // 0..1 (chunk2 = skq+2 -> src +16)
  const unsigned short* asrc =
      xp + (size_t)b * XPSTRIDE + (size_t)(t0 + srow) * HOP + skq * 8;
  int jc = j0 + srow;                      // B col; clamp cols >=1152
  if (jc > BCOLS - 1) jc = BCOLS - 1;      //  (padding reads row 1151, unstored)
  const unsigned short* bsrc = bmat + (size_t)jc * KTOT + skq * 8;

#define STAGE_A(KT, S)                                                         \
  __builtin_amdgcn_global_load_lds(GPTR(asrc + (KT) * BK),                     \
      LPTR(smemc + (S) * BUFBYTES + tid * 16), 16, 0, 0);                      \
  __builtin_amdgcn_global_load_lds(GPTR(asrc + (KT) * BK + 16),                \
      LPTR(smemc + (S) * BUFBYTES + 8192 + tid * 16), 16, 0, 0)
#define STAGE_B(KT, S)                                                         \
  __builtin_amdgcn_global_load_lds(GPTR(bsrc + (KT) * BK),                     \
      LPTR(smemc + (S) * BUFBYTES + TILEA + tid * 16), 16, 0, 0);              \
  __builtin_amdgcn_global_load_lds(GPTR(bsrc + (KT) * BK + 16),                \
      LPTR(smemc + (S) * BUFBYTES + TILEA + 8192 + tid * 16), 16, 0, 0)

  // ---- fragment LDS byte offsets (within a buffer) ----
  // af[mi]: chunk = quad*256 + wm*128 + mi*16 + L  (A[row][quad*8+j])
  // bf[ni]: chunk = quad*256 + wn*64  + ni*16 + L  (+TILEA)
  const int aoff = (quad * 256 + wm * 128 + L) * 16;
  const int boff = TILEA + (quad * 256 + wn * 64 + L) * 16;

  floatx4 acc[8][4] = {};
  short8 af[4], bf[4];

  // Phase 0 of tile (buf C): read af0-3 + bf0-3, stage A of tile KT2 -> S.
#define PHASE0(C, S, KT2, DOSTAGE)                                             \
  {                                                                            \
    const char* tb_ = smemc + (C) * BUFBYTES;                                  \
    _Pragma("unroll") for (int m = 0; m < 4; ++m)                              \
      af[m] = *(const short8*)(tb_ + aoff + m * 256);                          \
    _Pragma("unroll") for (int n = 0; n < 4; ++n)                              \
      bf[n] = *(const short8*)(tb_ + boff + n * 256);                          \
    if (DOSTAGE) { STAGE_A(KT2, S); }                                          \
    __builtin_amdgcn_s_barrier();                                              \
    __builtin_amdgcn_s_setprio(1);                                             \
    _Pragma("unroll") for (int m = 0; m < 4; ++m)                              \
      _Pragma("unroll") for (int n = 0; n < 4; ++n)                            \
        acc[m][n] = __builtin_amdgcn_mfma_f32_16x16x32_bf16(                   \
            af[m], bf[n], acc[m][n], 0, 0, 0);                                 \
    __builtin_amdgcn_s_setprio(0);                                             \
    __builtin_amdgcn_s_barrier();                                              \
  }
  // Phase 1: read af4-7 (bf kept in regs), stage B of KT2 -> S; end with
  // counted vmcnt(VM) BEFORE the barrier protecting the next tile's reads.
#define PHASE1(C, S, KT2, DOSTAGE, VM)                                         \
  {                                                                            \
    const char* tb_ = smemc + (C) * BUFBYTES;                                  \
    _Pragma("unroll") for (int m = 0; m < 4; ++m)                              \
      af[m] = *(const short8*)(tb_ + aoff + (m + 4) * 256);                    \
    if (DOSTAGE) { STAGE_B(KT2, S); }                                          \
    __builtin_amdgcn_s_barrier();                                              \
    __builtin_amdgcn_s_setprio(1);                                             \
    _Pragma("unroll") for (int m = 0; m < 4; ++m)                              \
      _Pragma("unroll") for (int n = 0; n < 4; ++n)                            \
        acc[m + 4][n] = __builtin_amdgcn_mfma_f32_16x16x32_bf16(               \
            af[m], bf[n], acc[m + 4][n], 0, 0, 0);                             \
    __builtin_amdgcn_s_setprio(0);                                             \
    asm volatile("s_waitcnt vmcnt(" #VM ")" ::: "memory");                     \
    __builtin_amdgcn_s_barrier();                                              \
  }

  // ---- prologue: stage tiles 0,1; wait tile 0 (drain to 4); sync ----
  STAGE_A(0, 0); STAGE_B(0, 0);
  STAGE_A(1, 1); STAGE_B(1, 1);
  asm volatile("s_waitcnt vmcnt(4)" ::: "memory");
  __builtin_amdgcn_s_barrier();

  // ---- main loop: tiles 0..29, buffers rotate mod 3, stage tile+2.
  // vmcnt ledger: 4 loads/tile issued; at each tile's end 8 outstanding ->
  // wait(4) drains exactly the next tile's 4. Never drained to 0 in-loop.
  for (int g = 0; g < 10; ++g) {
    const int k = 3 * g;
    PHASE0(0, 2, k + 2, 1);  PHASE1(0, 2, k + 2, 1, 4);
    PHASE0(1, 0, k + 3, 1);  PHASE1(1, 0, k + 3, 1, 4);
    PHASE0(2, 1, k + 4, 1);  PHASE1(2, 1, k + 4, 1, 4);
  }
  // ---- tail: tile 30 (buf0; drain tile 31's loads), tile 31 (buf1) ----
  PHASE0(0, 0, 0, 0);  PHASE1(0, 0, 0, 0, 0);
  PHASE0(1, 0, 0, 0);  PHASE1(1, 0, 0, 0, 0);

  // ---- epilogue: D[row = quad*4 + i][col = L] per 16x16 tile ----
#pragma unroll
  for (int mi = 0; mi < 8; ++mi) {
    const int tb = t0 + wm * 128 + mi * 16 + quad * 4;
#pragma unroll
    for (int ni = 0; ni < 4; ++ni) {
      const int gj = j0 + wn * 64 + ni * 16 + L;
      if (gj < NOUTROW) {
#pragma unroll
        for (int i = 0; i < 4; ++i) {
          const int t = tb + i;
          if (t < NFRAMES)
            out[(size_t)(b * NFRAMES + t) * NOUTROW + gj] = acc[mi][ni][i];
        }
      }
    }
  }
}

extern "C" void kernel_launch(void* const* d_in, const int* in_sizes, int n_in,
                              void* d_out, int out_size, void* d_ws, size_t ws_size,
                              hipStream_t stream) {
  const float* x   = (const float*)d_in[0];   // (16, 480000) fp32
  const float* win = (const float*)d_in[1];   // (1024,) fp32
  float* out = (float*)d_out;                 // (16, 1876, 513, 2) fp32

  unsigned short* xp   = (unsigned short*)d_ws;                  // 15.79 MB
  unsigned short* bmat = xp + (size_t)BATCH * XPSTRIDE;          // 2.36 MB

  (void)hipFuncSetAttribute((const void*)stft_gemm,
                            hipFuncAttributeMaxDynamicSharedMemorySize,
                            LDSBYTES);

  build_xp  <<<dim3(XPSTRIDE / 2048, BATCH), 256, 0, stream>>>(x, xp);
  build_bmat<<<dim3(BCOLS * (KTOT / 8) / 256), 256, 0, stream>>>(win, bmat);
  stft_gemm <<<dim3(BATCH * 8, 5), 512, LDSBYTES, stream>>>(xp, bmat, out);
}